// Round 1
// baseline (629.801 us; speedup 1.0000x reference)
//
#include <hip/hip_runtime.h>
#include <hip/hip_bf16.h>
#include <stdint.h>

typedef __bf16 bf16x8 __attribute__((ext_vector_type(8)));
typedef float f32x4 __attribute__((ext_vector_type(4)));
typedef unsigned short u16;
typedef u16 u16x8 __attribute__((ext_vector_type(8)));

// Problem constants: B=16, C=32, H=W=128, K=8 -> P=256, M=K=8192, N=1024.
#define MD 8192
#define KD 8192
#define ND 1024

__device__ __forceinline__ u16 f32_to_bf16(float f) {
  uint32_t u = __float_as_uint(f);
  u += 0x7FFFu + ((u >> 16) & 1u);   // round-to-nearest-even
  return (u16)(u >> 16);
}

__device__ __forceinline__ void load_lds16(const void* g, void* l) {
  __builtin_amdgcn_global_load_lds(
      (const __attribute__((address_space(1))) void*)g,
      (__attribute__((address_space(3))) void*)l, 16, 0, 0);
}

// ---- kernel 1: g (8192x8192 fp32, row-major [o][i]) -> bf16, same layout ----
__global__ void convert_g(const float* __restrict__ g, u16* __restrict__ gb) {
  size_t t = (size_t)blockIdx.x * 256 + threadIdx.x;   // 8388608 threads x 8 elems
  const float4* gp = (const float4*)g + t * 2;
  float4 a = gp[0], b = gp[1];
  u16x8 r;
  r[0] = f32_to_bf16(a.x); r[1] = f32_to_bf16(a.y);
  r[2] = f32_to_bf16(a.z); r[3] = f32_to_bf16(a.w);
  r[4] = f32_to_bf16(b.x); r[5] = f32_to_bf16(b.y);
  r[6] = f32_to_bf16(b.z); r[7] = f32_to_bf16(b.w);
  *((u16x8*)gb + t) = r;
}

// ---- kernel 2: build B^T = xf^T, shape (1024 cols x 8192 K), K contiguous ----
// col = n*64 + kk*8 + j ; i = ci*256 + hy*16 + wx ; B^T[col][i] = x[n,ci,hy*8+kk,wx*8+j]
__global__ void build_b(const float* __restrict__ x, u16* __restrict__ bt) {
  int t = blockIdx.x * 256 + threadIdx.x;              // 1048576 threads x 8 elems
  int i8  = t & 1023;
  int col = t >> 10;
  int n = col >> 6, kk = (col >> 3) & 7, j = col & 7;
  int i0 = i8 << 3;          // 8 consecutive i, same ci/hy
  int ci = i0 >> 8;
  int p0 = i0 & 255;
  int hy = p0 >> 4;
  int w0 = p0 & 15;          // 0 or 8
  const float* xb = x + ((size_t)((n << 5) + ci) * 128 + (hy << 3) + kk) * 128 + j;
  u16x8 r;
#pragma unroll
  for (int q = 0; q < 8; ++q)
    r[q] = f32_to_bf16(xb[(size_t)(w0 + q) << 3]);
  *((u16x8*)(bt + (size_t)col * KD + i0)) = r;         // 16B coalesced store
}

// ---- kernel 3: C = A * B^T  (both K-major), fused inverse-permute + residual ----
// 128x128 tile, BK=32, 4 waves each computing a 64x64 quadrant as 4x4 mfma frags.
__global__ __launch_bounds__(256) void gemm_bt(
    const u16* __restrict__ A,    // 8192 x 8192 bf16
    const u16* __restrict__ B,    // 1024 x 8192 bf16 (B^T)
    const float* __restrict__ X,  // residual (= x)
    float* __restrict__ out) {
  __shared__ u16 As[128 * 32];
  __shared__ u16 Bs[128 * 32];
  const int tid  = threadIdx.x;
  const int wave = tid >> 6;
  const int lane = tid & 63;
  const int m0 = blockIdx.y << 7;
  const int n0 = blockIdx.x << 7;

  // staging: per thread one 16B chunk per instr; 2 instrs per operand
  const int mst = (wave << 4) + (lane >> 2);           // 0..63
  const int kst = (lane & 3) << 3;                     // 0,8,16,24
  const u16* gA0 = A + (size_t)(m0 + mst) * KD + kst;
  const u16* gA1 = gA0 + (size_t)64 * KD;
  const u16* gB0 = B + (size_t)(n0 + mst) * KD + kst;
  const u16* gB1 = gB0 + (size_t)64 * KD;
  char* ldsA = (char*)As + (wave << 10);               // wave-uniform base
  char* ldsB = (char*)Bs + (wave << 10);

  const int wm = wave & 1, wn = wave >> 1;
  const int lm = lane & 15;
  const int kg = (lane >> 4) << 3;                     // k offset 0,8,16,24
  const u16* fA = As + ((wm << 6) + lm) * 32 + kg;
  const u16* fB = Bs + ((wn << 6) + lm) * 32 + kg;

  f32x4 acc[4][4];
#pragma unroll
  for (int i = 0; i < 4; ++i)
#pragma unroll
    for (int j = 0; j < 4; ++j)
      acc[i][j] = (f32x4){0.f, 0.f, 0.f, 0.f};

  for (int kt = 0; kt < KD / 32; ++kt) {
    const int k0 = kt << 5;
    __syncthreads();
    load_lds16(gA0 + k0, ldsA);
    load_lds16(gA1 + k0, ldsA + 4096);
    load_lds16(gB0 + k0, ldsB);
    load_lds16(gB1 + k0, ldsB + 4096);
    __syncthreads();
    bf16x8 av[4], bv[4];
#pragma unroll
    for (int i = 0; i < 4; ++i) {
      av[i] = *(const bf16x8*)(fA + i * 16 * 32);
      bv[i] = *(const bf16x8*)(fB + i * 16 * 32);
    }
#pragma unroll
    for (int i = 0; i < 4; ++i)
#pragma unroll
      for (int j = 0; j < 4; ++j)
        acc[i][j] = __builtin_amdgcn_mfma_f32_16x16x32_bf16(av[i], bv[j], acc[i][j], 0, 0, 0);
  }

  // epilogue: C/D layout col=lane&15, row=(lane>>4)*4+reg  [m89-verified]
  const int r4 = (lane >> 4) << 2;
#pragma unroll
  for (int i = 0; i < 4; ++i) {
    const int obase = m0 + (wm << 6) + (i << 4) + r4;
#pragma unroll
    for (int j = 0; j < 4; ++j) {
      const int cg = n0 + (wn << 6) + (j << 4) + lm;
      const int n = cg >> 6, kk = (cg >> 3) & 7, jj = cg & 7;
#pragma unroll
      for (int reg = 0; reg < 4; ++reg) {
        const int oo = obase + reg;
        const int co = oo >> 8, hy = (oo >> 4) & 15, wx = oo & 15;
        const size_t idx =
            ((size_t)((n << 5) + co) * 128 + (hy << 3) + kk) * 128 + (wx << 3) + jj;
        out[idx] = acc[i][j][reg] + X[idx];
      }
    }
  }
}

extern "C" void kernel_launch(void* const* d_in, const int* in_sizes, int n_in,
                              void* d_out, int out_size, void* d_ws, size_t ws_size,
                              hipStream_t stream) {
  const float* x = (const float*)d_in[0];       // (16,32,128,128) fp32
  const float* g = (const float*)d_in[1];       // (8192,8192) fp32
  float* out = (float*)d_out;                   // (16,32,128,128) fp32

  u16* gb = (u16*)d_ws;                         // 8192*8192 bf16 = 128 MiB
  u16* bt = gb + (size_t)MD * KD;               // 1024*8192 bf16 = 16 MiB

  convert_g<<<32768, 256, 0, stream>>>(g, gb);
  build_b<<<4096, 256, 0, stream>>>(x, bt);
  gemm_bt<<<dim3(ND / 128, MD / 128), 256, 0, stream>>>(gb, bt, x, out);
}